// Round 11
// baseline (601.026 us; speedup 1.0000x reference)
//
#include <hip/hip_runtime.h>
#include <hip/hip_bf16.h>
#include <math.h>

// ---- static config (matches reference) ----
#define B_      8
#define DIMC    512
#define SEQ_    784
#define HEADS_  8
#define DH_     64
#define NTOK    (B_*SEQ_)      // 6272
#define QLD     1560           // q(512) | k(512) | v(512) | gates(24)
#define WIN_    196
#define CBS_    392
#define CST_    196
#define NC_     3
#define EPSF    1e-5f
#define FF_     2048
#define TQ_     28             // queries per block (28*28 = 784)

typedef __hip_bfloat16 bf16_t;
typedef __attribute__((ext_vector_type(8))) short bf16x8;
typedef __attribute__((ext_vector_type(4))) float floatx4;
typedef __attribute__((ext_vector_type(4))) unsigned int uintx4;
typedef __attribute__((ext_vector_type(2))) unsigned int uintx2;

// ---------------- helpers ----------------
__device__ __forceinline__ float wsum(float x){
#pragma unroll
  for (int o = 32; o; o >>= 1) x += __shfl_xor(x, o, 64);
  return x;
}
__device__ __forceinline__ float geluf(float x){
  return 0.5f * x * (1.0f + erff(x * 0.70710678118654752f));
}
__device__ __forceinline__ float sigmoidf_(float x){
  return 1.0f / (1.0f + __expf(-x));
}
// async global->LDS 16B: dest is wave-uniform base + lane*16 (linear), src per-lane
__device__ __forceinline__ void gload16(const bf16_t* g, bf16_t* l){
  __builtin_amdgcn_global_load_lds(
      (const __attribute__((address_space(1))) void*)g,
      (__attribute__((address_space(3))) void*)l, 16, 0, 0);
}

// ---------------- init (tiled transpose): x[b,c,h,w] f32 -> X[b,p,c] f32 + pos ------
__global__ __launch_bounds__(256) void k_init(const float* __restrict__ xin,
                                              const float* __restrict__ pos,
                                              float* __restrict__ X){
  __shared__ float tl[32][33];
  int blk = blockIdx.x;              // 8 * 25 * 16
  int ct = blk & 15;
  int pt = (blk >> 4) % 25;
  int b  = blk / (16 * 25);
  int p0 = pt * 32, c0 = ct * 32;
  int tx = threadIdx.x & 31, ty = threadIdx.x >> 5;
#pragma unroll
  for (int i = 0; i < 4; i++){
    int p = p0 + tx;
    if (p < SEQ_) tl[ty + i * 8][tx] = xin[((long)(b * DIMC + c0 + ty + i * 8)) * SEQ_ + p];
  }
  __syncthreads();
#pragma unroll
  for (int i = 0; i < 4; i++){
    int p = p0 + ty + i * 8;
    if (p < SEQ_)
      X[((long)(b * SEQ_ + p)) * DIMC + c0 + tx] = tl[tx][ty + i * 8] + pos[p];
  }
}

// ---------------- final (tiled transpose): X[b,p,c] -> out[b,c,h,w] f32 -------------
__global__ __launch_bounds__(256) void k_final(const float* __restrict__ X,
                                               float* __restrict__ out){
  __shared__ float tl[32][33];
  int blk = blockIdx.x;              // 8 * 25 * 16
  int ct = blk & 15;
  int pt = (blk >> 4) % 25;
  int b  = blk / (16 * 25);
  int p0 = pt * 32, c0 = ct * 32;
  int tx = threadIdx.x & 31, ty = threadIdx.x >> 5;
#pragma unroll
  for (int i = 0; i < 4; i++){
    int p = p0 + ty + i * 8;
    if (p < SEQ_) tl[ty + i * 8][tx] = X[((long)(b * SEQ_ + p)) * DIMC + c0 + tx];
  }
  __syncthreads();
#pragma unroll
  for (int i = 0; i < 4; i++){
    int p = p0 + tx;
    if (p < SEQ_)
      out[((long)(b * DIMC + c0 + ty + i * 8)) * SEQ_ + p] = tl[tx][ty + i * 8];
  }
}

// ---------------- weight conversion (tiled): WQKVG [l][n][k] bf16 -------------------
__global__ __launch_bounds__(256) void k_wconv1(const float* __restrict__ Wq,
                                                const float* __restrict__ Wk,
                                                const float* __restrict__ Wv,
                                                const float* __restrict__ Wg,
                                                bf16_t* __restrict__ Wb){
  __shared__ float tl[32][33];
  int blk = blockIdx.x;              // 2 * 49 * 16
  int kt = blk & 15;
  int ntf = (blk >> 4) % 49;
  int l = blk / (16 * 49);
  int n0 = ntf * 32, k0 = kt * 32;
  int tx = threadIdx.x & 31, ty = threadIdx.x >> 5;
#pragma unroll
  for (int i = 0; i < 4; i++){
    int n = n0 + tx, k = k0 + ty + i * 8;
    float v = 0.0f;
    if (n < 1536){
      int which = n >> 9, nn = n & 511;
      const float* W = (which == 0) ? Wq : ((which == 1) ? Wk : Wv);
      v = W[((long)(l * 512 + k)) * 512 + nn];
    } else if (n < QLD){
      v = Wg[((long)(l * 512 + k)) * 24 + (n - 1536)];
    }
    tl[ty + i * 8][tx] = v;
  }
  __syncthreads();
#pragma unroll
  for (int i = 0; i < 4; i++){
    int n = n0 + ty + i * 8, k = k0 + tx;
    if (n < QLD)
      Wb[((long)(l * QLD + n)) * 512 + k] = __float2bfloat16(tl[tx][ty + i * 8]);
  }
}

// ---------------- WO transpose (tiled): Wb[l][n][k] = Wo[l][k][n] -------------------
__global__ __launch_bounds__(256) void k_wconv2(const float* __restrict__ Wo,
                                                bf16_t* __restrict__ Wb){
  __shared__ float tl[32][33];
  int blk = blockIdx.x;              // 2 * 16 * 16
  int kt = blk & 15;
  int ntf = (blk >> 4) & 15;
  int l = blk >> 8;
  int n0 = ntf * 32, k0 = kt * 32;
  int tx = threadIdx.x & 31, ty = threadIdx.x >> 5;
#pragma unroll
  for (int i = 0; i < 4; i++)
    tl[ty + i * 8][tx] = Wo[((long)(l * 512 + k0 + ty + i * 8)) * 512 + n0 + tx];
  __syncthreads();
#pragma unroll
  for (int i = 0; i < 4; i++)
    Wb[((long)(l * 512 + n0 + ty + i * 8)) * 512 + k0 + tx] = __float2bfloat16(tl[tx][ty + i * 8]);
}

// ---------------- plain f32 -> bf16 cast ----------------
__global__ __launch_bounds__(256) void k_cast(const float* __restrict__ src,
                                              bf16_t* __restrict__ dst){
  int idx = blockIdx.x * 256 + threadIdx.x;
  dst[idx] = __float2bfloat16(src[idx]);
}

// ---------------- 16B-granular zero fill ----------------
__global__ __launch_bounds__(256) void k_zero(uintx4* __restrict__ p){
  p[blockIdx.x * 256 + threadIdx.x] = (uintx4){0u, 0u, 0u, 0u};
}

// ---------------- RMSNorm: f32 in -> bf16 out ----------------
__global__ __launch_bounds__(256) void k_rms(const float* __restrict__ X,
                                             const float* __restrict__ g,
                                             bf16_t* __restrict__ XR){
  int tok = blockIdx.x;
  int tid = threadIdx.x;
  const float* xr = X + (long)tok * DIMC;
  float v0 = xr[tid], v1 = xr[tid + 256];
  float ss = v0 * v0 + v1 * v1;
  ss = wsum(ss);
  __shared__ float red[4];
  if ((tid & 63) == 0) red[tid >> 6] = ss;
  __syncthreads();
  float tot = red[0] + red[1] + red[2] + red[3];
  float r = rsqrtf(tot * (1.0f / DIMC) + EPSF);
  XR[(long)tok * DIMC + tid]       = __float2bfloat16(v0 * r * g[tid]);
  XR[(long)tok * DIMC + tid + 256] = __float2bfloat16(v1 * r * g[tid + 256]);
}

// ---------------- LayerNorm: f32 in -> bf16 out ----------------
__global__ __launch_bounds__(256) void k_ln(const float* __restrict__ X,
                                            const float* __restrict__ g,
                                            const float* __restrict__ bb,
                                            bf16_t* __restrict__ XN){
  int tok = blockIdx.x;
  int tid = threadIdx.x;
  const float* xr = X + (long)tok * DIMC;
  float v0 = xr[tid], v1 = xr[tid + 256];
  float s = v0 + v1;
  float q = v0 * v0 + v1 * v1;
  s = wsum(s); q = wsum(q);
  __shared__ float r1[4], r2[4];
  if ((tid & 63) == 0){ r1[tid >> 6] = s; r2[tid >> 6] = q; }
  __syncthreads();
  float ts = r1[0] + r1[1] + r1[2] + r1[3];
  float tq = r2[0] + r2[1] + r2[2] + r2[3];
  float mean = ts * (1.0f / DIMC);
  float var  = tq * (1.0f / DIMC) - mean * mean;
  float rinv = rsqrtf(var + EPSF);
  XN[(long)tok * DIMC + tid]       = __float2bfloat16((v0 - mean) * rinv * g[tid]       + bb[tid]);
  XN[(long)tok * DIMC + tid + 256] = __float2bfloat16((v1 - mean) * rinv * g[tid + 256] + bb[tid + 256]);
}

// ---------------- bf16 MFMA GEMM v5: BM x TN tile, BK chunk, optional split-K -------
// SPLITK=2 (WO, FF2 — K-deep, small-N, serial-chain-bound per R10 counters:
// MfmaUtil 8%, Occ 15%): grid doubles, block id bit0 selects K-half, epilogue
// atomicAdds into Cf (X). X already holds the residual; bias added by the ks=0
// half only. Halves the 32-chunk serial chain AND doubles block TLP.
// SPLITK=1 (QKVG, FF1): unchanged R10 behavior.
template<int OUTBF, int ACT, int BM, int TN, int BK, int SPLITK>
__global__ __launch_bounds__(256) void k_mgemm(const bf16_t* __restrict__ A,
                                               const bf16_t* __restrict__ Bm,
                                               float* Cf,
                                               bf16_t* Cb,
                                               const float* __restrict__ bias,
                                               const float* res,
                                               int N, int K, int ldc,
                                               bf16_t* VTo){
  constexpr int MTILES = NTOK / BM;        // 98 or 49
  constexpr int MPX  = (MTILES + 7) / 8;   // m-groups per XCD (13 or 7)
  constexpr int MF   = BM / 32;            // m-frags per wave (2 or 4)
  constexpr int NF   = TN / 32;            // n-frags per wave (2 or 4)
  constexpr int KS   = BK / 32;            // k-steps per chunk (1 or 2)
  constexpr int RPB2 = 512 / BK;           // rows per 1KB wave-block
  constexpr int LPR  = BK / 8;             // lanes per row
  constexpr int ABLK = (BM * BK) / 512;    // A wave-blocks per chunk
  constexpr int BBLK = (TN * BK) / 512;    // B wave-blocks per chunk
  constexpr int TOT  = ABLK + BBLK;
  constexpr int PW   = TOT / 4;            // blocks per wave
  static_assert(TOT % 4 == 0, "stage blocks must split across 4 waves");

  int id = blockIdx.x;
  int ks2 = 0;
  if (SPLITK == 2){ ks2 = id & 1; id >>= 1; }
  int xcd = id & 7;
  int j = id >> 3;
  int nt = j / MPX;
  int mt = xcd * MPX + (j - nt * MPX);
  if (mt >= MTILES) return;
  int bm = mt * BM, bn = nt * TN;

  int Keff = (SPLITK == 2) ? (K >> 1) : K;
  if (SPLITK == 2){           // shift both operands to this K-half (row stride stays K)
    A  += ks2 * Keff;
    Bm += ks2 * Keff;
  }

  __shared__ bf16_t As[2][BM][BK];         // unpadded (gload_lds requires linear)
  __shared__ bf16_t Bs[2][TN][BK];
  int tid = threadIdx.x;
  int w = tid >> 6, lane = tid & 63;
  int wm = (w & 1) * (BM / 2), wn = (w >> 1) * (TN / 2);
  int quad = lane >> 4, l16 = lane & 15;

  // staging assignment: wave w owns blocks w*PW .. w*PW+PW-1 (A-blocks first)
  int lr = lane / LPR, lc = (lane % LPR) * 8;
  const bf16_t* gsrc[PW];
  bf16_t* ldst0[PW];
  bf16_t* ldst1[PW];
#pragma unroll
  for (int i = 0; i < PW; i++){
    int bi = w * PW + i;
    if (bi < ABLK){
      gsrc[i]  = A + (long)(bm + bi * RPB2 + lr) * K + lc;
      ldst0[i] = &As[0][bi * RPB2][0];
      ldst1[i] = &As[1][bi * RPB2][0];
    } else {
      int bj = bi - ABLK;
      int r = bn + bj * RPB2 + lr; if (r >= N) r = N - 1;
      gsrc[i]  = Bm + (long)r * K + lc;
      ldst0[i] = &Bs[0][bj * RPB2][0];
      ldst1[i] = &Bs[1][bj * RPB2][0];
    }
  }

  floatx4 acc[MF][NF];
#pragma unroll
  for (int i = 0; i < MF; i++)
#pragma unroll
    for (int jj = 0; jj < NF; jj++) acc[i][jj] = (floatx4)(0.0f);

#define MG_STAGE0(ko) do { _Pragma("unroll") \
    for (int i_ = 0; i_ < PW; i_++) gload16(gsrc[i_] + (ko), ldst0[i_]); } while (0)
#define MG_STAGE1(ko) do { _Pragma("unroll") \
    for (int i_ = 0; i_ < PW; i_++) gload16(gsrc[i_] + (ko), ldst1[i_]); } while (0)
#define MG_COMPUTE(BUFI) do { _Pragma("unroll") \
    for (int ks_ = 0; ks_ < KS; ks_++){ \
      bf16x8 af_[MF], bf_[NF]; \
      _Pragma("unroll") \
      for (int m_ = 0; m_ < MF; m_++) \
        af_[m_] = *(bf16x8*)&As[BUFI][wm + m_ * 16 + l16][ks_ * 32 + quad * 8]; \
      _Pragma("unroll") \
      for (int f_ = 0; f_ < NF; f_++) \
        bf_[f_] = *(bf16x8*)&Bs[BUFI][wn + f_ * 16 + l16][ks_ * 32 + quad * 8]; \
      _Pragma("unroll") \
      for (int m_ = 0; m_ < MF; m_++) \
        _Pragma("unroll") \
        for (int f_ = 0; f_ < NF; f_++) \
          acc[m_][f_] = __builtin_amdgcn_mfma_f32_16x16x32_bf16(af_[m_], bf_[f_], acc[m_][f_], 0, 0, 0); \
    } } while (0)

  int nch = Keff / BK;                     // even in all uses
  MG_STAGE0(0);
  __syncthreads();
  for (int ch = 0; ch < nch; ch += 2){
    MG_STAGE1((ch + 1) * BK);              // prefetch odd chunk (flies under MFMAs)
    MG_COMPUTE(0);
    __syncthreads();                       // drains prefetch + orders buf0 rewrite
    if (ch + 2 < nch) MG_STAGE0((ch + 2) * BK);
    MG_COMPUTE(1);
    __syncthreads();
  }
#undef MG_STAGE0
#undef MG_STAGE1
#undef MG_COMPUTE

#pragma unroll
  for (int tm = 0; tm < MF; tm++){
#pragma unroll
    for (int tn = 0; tn < NF; tn++){
      int ncol = bn + wn + tn * 16 + l16;
      if (ncol >= N) continue;
#pragma unroll
      for (int reg = 0; reg < 4; reg++){
        long mrow = bm + wm + tm * 16 + quad * 4 + reg;
        float v = acc[tm][tn][reg];
        long off = mrow * (long)ldc + ncol;
        if (SPLITK == 2){
          if (ks2 == 0 && bias) v += bias[ncol];
          atomicAdd(&Cf[off], v);          // X holds residual; adds commute
        } else {
          if (bias) v += bias[ncol];
          if (ACT == 1) v = geluf(v);
          if (res) v += res[off];
          if (OUTBF){
            Cb[off] = __float2bfloat16(v);
            if (VTo && ncol >= 1024 && ncol < 1536){
              int bb2 = (int)(mrow / SEQ_);
              int tok = (int)(mrow - (long)bb2 * SEQ_);
              VTo[((long)(bb2 * 512 + (ncol - 1024))) * 800 + tok] = __float2bfloat16(v);
            }
          }
          else Cf[off] = v;
        }
      }
    }
  }
}

// ---------------- compressed-block mean pooling v2: 8-way channel split -------------
__global__ __launch_bounds__(256) void k_cpool(const bf16_t* __restrict__ qkvg,
                                               float* __restrict__ ck,
                                               float* __restrict__ cv){
  int blk = blockIdx.x;          // B_*NC_*8
  int cs = blk & 7;
  int bj = blk >> 3;
  int j = bj % NC_;
  int b = bj / NC_;
  int tid = threadIdx.x;
  int seg = tid & 15;            // 16 lanes x 8 ch = 128 channels
  int rg  = tid >> 4;            // 16 row-groups
  __shared__ float part[16][128];
  const bf16_t* base = qkvg + ((long)b * SEQ_ + (long)j * CST_) * QLD + 512 + cs * 128;
  float acc[8] = {0.f,0.f,0.f,0.f,0.f,0.f,0.f,0.f};
  for (int r = rg; r < CBS_; r += 16){
    uintx4 v = *(const uintx4*)(base + (long)r * QLD + seg * 8);
    bf16_t tmp[8]; *(uintx4*)tmp = v;
#pragma unroll
    for (int q = 0; q < 8; q++) acc[q] += __bfloat162float(tmp[q]);
  }
#pragma unroll
  for (int q = 0; q < 8; q++) part[rg][seg * 8 + q] = acc[q];
  __syncthreads();
  if (tid < 128){
    float s = 0.f;
#pragma unroll
    for (int g = 0; g < 16; g++) s += part[g][tid];
    s *= (1.0f / CBS_);
    int gch = cs * 128 + tid;
    if (gch < 512) ck[bj * DIMC + gch] = s;
    else           cv[bj * DIMC + (gch - 512)] = s;
  }
}

// ---------------- fused NSA attention v11 (frozen; 57.9 us) -------------------------
__global__ __launch_bounds__(256) void k_attn(const bf16_t* __restrict__ qkvg,
                                              const float* __restrict__ ck,
                                              const float* __restrict__ cv,
                                              const bf16_t* __restrict__ vtg,
                                              bf16_t* __restrict__ oattn){
  int tid = threadIdx.x;
  int w = tid >> 6, lane = tid & 63;
  int quad = lane >> 4, l16 = lane & 15;
  int id = blockIdx.x;
  int xcd = id & 7;
  int j = id >> 3;               // 0..223
  int bh = xcd * 8 + (j / 28);   // all 28 tiles of a bh on one XCD
  int i0 = (j % 28) * TQ_;
  int h = bh & 7, b = bh >> 3;
  const float scale = 0.125f;

  __shared__ bf16_t Qs[32][72];          // rows 28-31 zero
  __shared__ bf16_t Ks[2][64][72];       // K dbuf
  __shared__ bf16_t Wcw[2][32][72];      // win-masked W dbuf (rows 28-31 zero)
  __shared__ bf16_t Wcs[2][32][72];      // sel-masked W dbuf (rows 28-31 zero)
  __shared__ float outc_s[28][64];
  __shared__ int   sel_s[28];
  __shared__ float cw_s[28], cs_s[28], g1_s[28], g2_s[28];
  __shared__ float red_s[4][4][16];

  const long rowBase = (long)b * SEQ_ * QLD + h * 64;     // + token*QLD + {0,512,1024}

  // ---- Phase A: stage Q tile (28 rows) + zero rows 28-31; zero Wc rows 28-31 ----
  if (tid < 224){
    int q = tid >> 3, seg = tid & 7;
    uintx4 qv = *(const uintx4*)(qkvg + rowBase + (long)(i0 + q) * QLD + seg * 8);
    *(uintx4*)&Qs[q][seg * 8] = qv;
  } else {
    int u = tid - 224;
    int r = 28 + (u >> 3), seg = u & 7;
    *(uintx4*)&Qs[r][seg * 8] = (uintx4){0u, 0u, 0u, 0u};
  }
  for (int t = tid; t < 2 * 4 * 72; t += 256){
    int bufi = t / (4 * 72);
    int r = 28 + (t / 72) % 4;
    int c = t % 72;
    Wcw[bufi][r][c] = __float2bfloat16(0.0f);
    Wcs[bufi][r][c] = __float2bfloat16(0.0f);
  }
  __syncthreads();

  // ---- prefetch K chunk 0 (latency hidden under Phase B) ----
  int r0i = tid >> 3, s0i = tid & 7;
  int r1i = 32 + r0i;
  uintx4 kreg0 = *(const uintx4*)(qkvg + rowBase + (long)r0i * QLD + 512 + s0i * 8);
  uintx4 kreg1 = *(const uintx4*)(qkvg + rowBase + (long)r1i * QLD + 512 + s0i * 8);

  // ---- Phase B: compressed branch + gates + top-1 selection ----
  {
    const float* CKp = ck + (long)b * NC_ * DIMC + h * 64 + lane;
    const float* CVp = cv + (long)b * NC_ * DIMC + h * 64 + lane;
    float k0 = CKp[0], k1 = CKp[512], k2 = CKp[1024];
    float v0 = CVp[0], v1 = CVp[512], v2 = CVp[1024];
#pragma unroll
    for (int qp = 0; qp < 7; qp++){
      int qg = w * 7 + qp;
      float qd = __bfloat162float(Qs[qg][lane]);
      float s0 = wsum(qd * k0) * scale;
      float s1 = wsum(qd * k1) * scale;
      float s2 = wsum(qd * k2) * scale;
      float m3 = fmaxf(s0, fmaxf(s1, s2));
      float e0 = __expf(s0 - m3), e1 = __expf(s1 - m3), e2 = __expf(s2 - m3);
      float inv = 1.0f / (e0 + e1 + e2);
      const bf16_t* grow = qkvg + (long)(b * SEQ_ + i0 + qg) * QLD + 1536 + h * 3;
      float g0 = sigmoidf_(__bfloat162float(grow[0]));
      float g1v = sigmoidf_(__bfloat162float(grow[1]));
      float g2v = sigmoidf_(__bfloat162float(grow[2]));
      outc_s[qg][lane] = g0 * (e0 * v0 + e1 * v1 + e2 * v2) * inv;
      int selv = (s2 > s0) ? 1 : 0;   // imp1>imp0 <=> p2>p0 <=> s2>s0
      if (lane == 0){ sel_s[qg] = selv; g1_s[qg] = g1v; g2_s[qg] = g2v; }
    }
  }

  // hoist Q B-fragments (chunk-invariant)
  bf16x8 a00 = *(bf16x8*)&Qs[l16][quad * 8];
  bf16x8 a01 = *(bf16x8*)&Qs[l16][32 + quad * 8];
  bf16x8 a10 = *(bf16x8*)&Qs[16 + l16][quad * 8];
  bf16x8 a11 = *(bf16x8*)&Qs[16 + l16][32 + quad * 8];

  __syncthreads();   // sel_s/g1_s/g2_s visible; Wc zero rows done

  // ---- selection-half usage flags (block-uniform) ----
  int nsel1 = 0;
#pragma unroll
  for (int q = 0; q < 28; q++) nsel1 += sel_s[q];
  const bool any0 = (nsel1 < 28), any1 = (nsel1 > 0);

  // ---- main loop: 13 chunks of 64 keys, fused QK^T + masked-W + PV ----------------
  int sel0i = sel_s[l16];
  int sel1i = (l16 < 12) ? sel_s[16 + l16] : 0;
  bool sv0 = (sel0i != 0), sv1 = (sel1i != 0);
  int iq0 = i0 + l16, iq1 = i0 + 16 + l16;
  float sw0 = 0.f, ss0 = 0.f, sw1 = 0.f, ss1 = 0.f;

  const bf16_t* vbase = vtg + ((long)(b * 512 + h * 64 + w * 16 + l16)) * 800;
  floatx4 ow0 = (floatx4)(0.0f), ow1 = (floatx4)(0.0f);
  floatx4 os0 = (floatx4)(0.0f), os1 = (floatx4)(0.0f);

  for (int ch = 0; ch < 13; ch++){
    int buf = ch & 1;
    int K0 = ch * 64;
    // block-uniform activity flags for this chunk
    bool wact = (K0 + 63 >= i0 - 195) && (K0 <= i0 + 222);
    bool sact = ((K0 <= 391) && any0) || ((K0 + 63 >= 392) && any1);
    bool pact = wact || sact;
    // stage K chunk
    *(uintx4*)&Ks[buf][r0i][s0i * 8] = kreg0;
    *(uintx4*)&Ks[buf][r1i][s0i * 8] = kreg1;
    __syncthreads();                               // barrier A
    // prefetch next K chunk
    if (ch + 1 < 13){
      int c0n = (ch + 1) * 64;
      int t0 = c0n + r0i; if (t0 > 783) t0 = 783;
      int t1 = c0n + r1i; if (t1 > 783) t1 = 783;
      kreg0 = *(const uintx4*)(qkvg + rowBase + (long)t0 * QLD + 512 + s0i * 8);
      kreg1 = *(const uintx4*)(qkvg + rowBase + (long)t1 * QLD + 512 + s0i * 8);
    }
    // V^T fragments for this chunk (latency hides under QK^T+exp)
    int tv0 = K0 + quad * 8;      if (tv0 > 792) tv0 = 792;
    int tv1 = K0 + 32 + quad * 8; if (tv1 > 792) tv1 = 792;
    bf16x8 bv0 = *(const bf16x8*)(vbase + tv0);
    bf16x8 bv1 = *(const bf16x8*)(vbase + tv1);
    if (pact){
      // QK^T (S^T layout: lane holds q=l16 / 16+l16, keys K0+w*16+quad*4+{0..3})
      bf16x8 k0 = *(bf16x8*)&Ks[buf][w * 16 + l16][quad * 8];
      bf16x8 k1 = *(bf16x8*)&Ks[buf][w * 16 + l16][32 + quad * 8];
      floatx4 d0 = (floatx4)(0.0f), d1 = (floatx4)(0.0f);
      d0 = __builtin_amdgcn_mfma_f32_16x16x32_bf16(k0, a00, d0, 0, 0, 0);
      d0 = __builtin_amdgcn_mfma_f32_16x16x32_bf16(k1, a01, d0, 0, 0, 0);
      d1 = __builtin_amdgcn_mfma_f32_16x16x32_bf16(k0, a10, d1, 0, 0, 0);
      d1 = __builtin_amdgcn_mfma_f32_16x16x32_bf16(k1, a11, d1, 0, 0, 0);
      int kb = K0 + w * 16 + quad * 4;
      float ex0[4], ex1[4];
#pragma unroll
      for (int r = 0; r < 4; r++){
        ex0[r] = __expf(d0[r] * scale);
        ex1[r] = __expf(d1[r] * scale);
      }
      int kloc = w * 16 + quad * 4;
      if (wact){
        union { bf16_t hh[4]; uintx2 v; } pw0, pw1;
#pragma unroll
        for (int r = 0; r < 4; r++){
          int key = kb + r;
          bool valid = key < 784;
          float vw0 = (valid && key >= iq0 - 195 && key <= iq0 + 195) ? ex0[r] : 0.0f;
          float vw1 = (valid && key >= iq1 - 195 && key <= iq1 + 195) ? ex1[r] : 0.0f;
          sw0 += vw0; sw1 += vw1;
          pw0.hh[r] = __float2bfloat16(vw0);
          pw1.hh[r] = __float2bfloat16(vw1);
        }
        if (kb < 784){
          *(uintx2*)&Wcw[buf][l16][kloc] = pw0.v;
          if (l16 < 12) *(uintx2*)&Wcw[buf][16 + l16][kloc] = pw1.v;
        }
      }
      if (sact){
        union { bf16_t hh[4]; uintx2 v; } ps0, ps1;
#pragma unroll
        for (int r = 0; r < 4; r++){
          int key = kb + r;
          bool valid = key < 784;
          float vs0 = (valid && ((key >= 392) == sv0)) ? ex0[r] : 0.0f;
          float vs1 = (valid && ((key >= 392) == sv1)) ? ex1[r] : 0.0f;
          ss0 += vs0; ss1 += vs1;
          ps0.hh[r] = __float2bfloat16(vs0);
          ps1.hh[r] = __float2bfloat16(vs1);
        }
        if (kb < 784){
          *(uintx2*)&Wcs[buf][l16][kloc] = ps0.v;
          if (l16 < 12) *(uintx2*)&Wcs[buf][16 + l16][kloc] = ps1.v;
        }
      }
    }
    __syncthreads();                               // barrier B
    // PV: wave w owns d = w*16+l16; A = Wc rows (q), B = V^T
    if (wact){
#pragma unroll
      for (int ks = 0; ks < 2; ks++){
        bf16x8 bv = ks ? bv1 : bv0;
        bf16x8 aw0 = *(bf16x8*)&Wcw[buf][l16][ks * 32 + quad * 8];
        bf16x8 aw1 = *(bf16x8*)&Wcw[buf][16 + l16][ks * 32 + quad * 8];
        ow0 = __builtin_amdgcn_mfma_f32_16x16x32_bf16(aw0, bv, ow0, 0, 0, 0);
        ow1 = __builtin_amdgcn_mfma_f32_16x16x32_bf16(aw1, bv, ow1, 0, 0, 0);
      }
    }
    if (sact){
#pragma unroll
      for (int ks = 0; ks < 2; ks++){
        bf16x8 bv = ks ? bv1 : bv0;
        bf16x8 as0 = *(bf16x8*)&Wcs[buf][l16][ks * 32 + quad * 8];
        bf16x8 as1 = *(bf16x8*)&Wcs[buf][16 + l16][ks * 32 + quad * 8];
        os0 = __builtin_amdgcn_mfma_f32_16x16x32_bf16(as0, bv, os0, 0, 0, 0);
        os1 = __builtin_amdgcn_mfma_f32_16x16x32_bf16(as1, bv, os1, 0, 0, 0);
      }
    }
  }

  // ---- combine row sums: quads via shfl, waves via 1KB LDS ----
  sw0 += __shfl_xor(sw0, 16, 64); sw0 += __shfl_xor(sw0, 32, 64);
  ss0 += __shfl_xor(ss0, 16, 64); ss0 += __shfl_xor(ss0, 32, 64);
  sw1 += __shfl_xor(sw1, 16, 64); sw1 += __shfl_xor(sw1, 32, 64);
  ss1 += __shfl_xor(ss1, 16, 64); ss1 += __shfl_xor(ss1, 32, 64);
  if (quad == 0){
    red_s[w][0][l16] = sw0; red_s[w][1][l16] = ss0;
    red_s[w][2][l16] = sw1; red_s[w][3][l16] = ss1;
  }
  __syncthreads();
  if (tid < 28){
    int q = tid, t = q >> 4, l = q & 15;
    float sw = 0.f, ss = 0.f;
#pragma unroll
    for (int wv = 0; wv < 4; wv++){ sw += red_s[wv][2 * t][l]; ss += red_s[wv][2 * t + 1][l]; }
    cw_s[q] = g2_s[q] / sw;
    cs_s[q] = g1_s[q] / ss;
  }
  __syncthreads();

  // ---- epilogue: scale branches, add compressed branch, write bf16 ----
  int d = w * 16 + l16;
#pragma unroll
  for (int reg = 0; reg < 4; reg++){
    int q = quad * 4 + reg;
    float o = cw_s[q] * ow0[reg] + cs_s[q] * os0[reg] + outc_s[q][d];
    oattn[((long)(b * SEQ_ + i0 + q)) * DIMC + h * 64 + d] = __float2bfloat16(o);
    int q2 = q + 16;
    if (q2 < 28){
      float o2 = cw_s[q2] * ow1[reg] + cs_s[q2] * os1[reg] + outc_s[q2][d];
      oattn[((long)(b * SEQ_ + i0 + q2)) * DIMC + h * 64 + d] = __float2bfloat16(o2);
    }
  }
}

// ---------------- host launcher ----------------
extern "C" void kernel_launch(void* const* d_in, const int* in_sizes, int n_in,
                              void* d_out, int out_size, void* d_ws, size_t ws_size,
                              hipStream_t stream){
  const float* xin  = (const float*)d_in[0];
  const float* pos  = (const float*)d_in[1];
  const float* angm = (const float*)d_in[2];
  const float* Wq   = (const float*)d_in[3];
  const float* Wk   = (const float*)d_in[4];
  const float* Wv   = (const float*)d_in[5];
  const float* Wo   = (const float*)d_in[6];
  const float* Wg   = (const float*)d_in[7];
  const float* fng  = (const float*)d_in[8];
  const float* fnb  = (const float*)d_in[9];
  const float* fw1  = (const float*)d_in[10];
  const float* fb1  = (const float*)d_in[11];
  const float* fw2  = (const float*)d_in[12];
  const float* fb2  = (const float*)d_in[13];

  // workspace layout: ~70.7 MB total (BUFb/H1b share one region — disjoint live ranges)
  char* cw = (char*)d_ws;
  float* X = (float*)cw;             cw += (long)NTOK * 512 * 4;     // 12.85 MB
  bf16_t* XRb = (bf16_t*)cw;         cw += (long)NTOK * 512 * 2;     //  6.42 MB
  bf16_t* OAb = (bf16_t*)cw;         cw += (long)NTOK * 512 * 2;     //  6.42 MB
  bf16_t* SH  = (bf16_t*)cw;         cw += (long)NTOK * FF_ * 2;     // 25.69 MB (BUFb/H1b)
  float* CK = (float*)cw;            cw += (long)B_ * NC_ * DIMC * 4;
  float* CV = (float*)cw;            cw += (long)B_ * NC_ * DIMC * 4;
  bf16_t* Wqkvgb = (bf16_t*)cw;      cw += (long)2 * QLD * 512 * 2;  //  3.19 MB
  bf16_t* WOb    = (bf16_t*)cw;      cw += (long)2 * 512 * 512 * 2;  //  1.05 MB
  bf16_t* FW1b   = (bf16_t*)cw;      cw += (long)2 * FF_ * 512 * 2;  //  4.19 MB
  bf16_t* FW2b   = (bf16_t*)cw;      cw += (long)2 * 512 * FF_ * 2;  //  4.19 MB
  bf16_t* VTb    = (bf16_t*)cw;      cw += (long)B_ * 512 * 800 * 2; //  6.55 MB
  bf16_t* BUFb = SH;   // [NTOK, QLD]  (QKVG output; dies after k_attn)
  bf16_t* H1b  = SH;   // [NTOK, FF_]  (FF1 output; born after k_ln)

  // per-call weight conversion (deterministic, same work every call)
  k_wconv1<<<2 * 49 * 16, 256, 0, stream>>>(Wq, Wk, Wv, Wg, Wqkvgb);
  k_wconv2<<<2 * 16 * 16, 256, 0, stream>>>(Wo, WOb);
  k_cast<<<(2 * FF_ * 512) / 256, 256, 0, stream>>>(fw1, FW1b);
  k_cast<<<(2 * 512 * FF_) / 256, 256, 0, stream>>>(fw2, FW2b);

  // zero VT once: tokens 784..799 stay zero; cols 0..783 rewritten each layer
  k_zero<<<1600, 256, 0, stream>>>((uintx4*)VTb);   // 6,553,600 B

  k_init<<<8 * 25 * 16, 256, 0, stream>>>(xin, pos, X);

  for (int l = 0; l < 2; l++){
    k_rms<<<NTOK, 256, 0, stream>>>(X, angm + (long)l * DIMC, XRb);

    // fused QKV+G GEMM: [6272,512] x [1560,512]^T -> BUFb [6272,1560] bf16 (+ VT)
    k_mgemm<1, 0, 128, 128, 32, 1><<<13 * 56, 256, 0, stream>>>(
        XRb, Wqkvgb + (long)l * QLD * 512, nullptr, BUFb, nullptr, nullptr,
        QLD, 512, QLD, VTb);

    k_cpool<<<B_ * NC_ * 8, 256, 0, stream>>>(BUFb, CK, CV);

    k_attn<<<8 * 8 * 28, 256, 0, stream>>>(BUFb, CK, CV, VTb, OAb);

    // Wo GEMM: split-K=2 atomicAdd into X (X holds residual), grid 2x832
    k_mgemm<0, 0, 64, 64, 64, 2><<<2 * 8 * 104, 256, 0, stream>>>(
        OAb, WOb + (long)l * 512 * 512, X, nullptr, nullptr, nullptr,
        512, 512, 512, nullptr);

    k_ln<<<NTOK, 256, 0, stream>>>(X, fng + (long)l * DIMC, fnb + (long)l * DIMC, XRb);

    // FF1 + GELU, bf16 out into H1b (BM=128, grid 16 nt x 56)
    k_mgemm<1, 1, 128, 128, 32, 1><<<16 * 56, 256, 0, stream>>>(
        XRb, FW1b + (long)l * FF_ * 512, nullptr, H1b, fb1 + (long)l * FF_, nullptr,
        FF_, 512, FF_, nullptr);
    // FF2: split-K=2 atomicAdd into X (+fb2 from ks=0 half), grid 2x832
    k_mgemm<0, 0, 64, 64, 64, 2><<<2 * 8 * 104, 256, 0, stream>>>(
        H1b, FW2b + (long)l * 512 * FF_, X, nullptr, fb2 + (long)l * DIMC, nullptr,
        512, FF_, 512, nullptr);
  }

  k_final<<<8 * 25 * 16, 256, 0, stream>>>(X, (float*)d_out);
}

// Round 13
// 547.028 us; speedup vs baseline: 1.0987x; 1.0987x over previous
//
#include <hip/hip_runtime.h>
#include <hip/hip_bf16.h>
#include <math.h>

// ---- static config (matches reference) ----
#define B_      8
#define DIMC    512
#define SEQ_    784
#define HEADS_  8
#define DH_     64
#define NTOK    (B_*SEQ_)      // 6272
#define QLD     1560           // q(512) | k(512) | v(512) | gates(24)
#define WIN_    196
#define CBS_    392
#define CST_    196
#define NC_     3
#define EPSF    1e-5f
#define FF_     2048
#define TQ_     28             // queries per block (28*28 = 784)

typedef __hip_bfloat16 bf16_t;
typedef __attribute__((ext_vector_type(8))) short bf16x8;
typedef __attribute__((ext_vector_type(4))) float floatx4;
typedef __attribute__((ext_vector_type(4))) unsigned int uintx4;
typedef __attribute__((ext_vector_type(2))) unsigned int uintx2;

// ---------------- helpers ----------------
__device__ __forceinline__ float wsum(float x){
#pragma unroll
  for (int o = 32; o; o >>= 1) x += __shfl_xor(x, o, 64);
  return x;
}
__device__ __forceinline__ float geluf(float x){
  return 0.5f * x * (1.0f + erff(x * 0.70710678118654752f));
}
__device__ __forceinline__ float sigmoidf_(float x){
  return 1.0f / (1.0f + __expf(-x));
}
// async global->LDS 16B: dest is wave-uniform base + lane*16 (linear), src per-lane
__device__ __forceinline__ void gload16(const bf16_t* g, bf16_t* l){
  __builtin_amdgcn_global_load_lds(
      (const __attribute__((address_space(1))) void*)g,
      (__attribute__((address_space(3))) void*)l, 16, 0, 0);
}

// ---------------- init (tiled transpose): x[b,c,h,w] f32 -> X[b,p,c] f32 + pos ------
__global__ __launch_bounds__(256) void k_init(const float* __restrict__ xin,
                                              const float* __restrict__ pos,
                                              float* __restrict__ X){
  __shared__ float tl[32][33];
  int blk = blockIdx.x;              // 8 * 25 * 16
  int ct = blk & 15;
  int pt = (blk >> 4) % 25;
  int b  = blk / (16 * 25);
  int p0 = pt * 32, c0 = ct * 32;
  int tx = threadIdx.x & 31, ty = threadIdx.x >> 5;
#pragma unroll
  for (int i = 0; i < 4; i++){
    int p = p0 + tx;
    if (p < SEQ_) tl[ty + i * 8][tx] = xin[((long)(b * DIMC + c0 + ty + i * 8)) * SEQ_ + p];
  }
  __syncthreads();
#pragma unroll
  for (int i = 0; i < 4; i++){
    int p = p0 + ty + i * 8;
    if (p < SEQ_)
      X[((long)(b * SEQ_ + p)) * DIMC + c0 + tx] = tl[tx][ty + i * 8] + pos[p];
  }
}

// ---------------- final (tiled transpose): X[b,p,c] -> out[b,c,h,w] f32 -------------
__global__ __launch_bounds__(256) void k_final(const float* __restrict__ X,
                                               float* __restrict__ out){
  __shared__ float tl[32][33];
  int blk = blockIdx.x;              // 8 * 25 * 16
  int ct = blk & 15;
  int pt = (blk >> 4) % 25;
  int b  = blk / (16 * 25);
  int p0 = pt * 32, c0 = ct * 32;
  int tx = threadIdx.x & 31, ty = threadIdx.x >> 5;
#pragma unroll
  for (int i = 0; i < 4; i++){
    int p = p0 + ty + i * 8;
    if (p < SEQ_) tl[ty + i * 8][tx] = X[((long)(b * SEQ_ + p)) * DIMC + c0 + tx];
  }
  __syncthreads();
#pragma unroll
  for (int i = 0; i < 4; i++){
    int p = p0 + tx;
    if (p < SEQ_)
      out[((long)(b * DIMC + c0 + ty + i * 8)) * SEQ_ + p] = tl[tx][ty + i * 8];
  }
}

// ---------------- weight conversion (tiled): WQKVG [l][n][k] bf16 -------------------
__global__ __launch_bounds__(256) void k_wconv1(const float* __restrict__ Wq,
                                                const float* __restrict__ Wk,
                                                const float* __restrict__ Wv,
                                                const float* __restrict__ Wg,
                                                bf16_t* __restrict__ Wb){
  __shared__ float tl[32][33];
  int blk = blockIdx.x;              // 2 * 49 * 16
  int kt = blk & 15;
  int ntf = (blk >> 4) % 49;
  int l = blk / (16 * 49);
  int n0 = ntf * 32, k0 = kt * 32;
  int tx = threadIdx.x & 31, ty = threadIdx.x >> 5;
#pragma unroll
  for (int i = 0; i < 4; i++){
    int n = n0 + tx, k = k0 + ty + i * 8;
    float v = 0.0f;
    if (n < 1536){
      int which = n >> 9, nn = n & 511;
      const float* W = (which == 0) ? Wq : ((which == 1) ? Wk : Wv);
      v = W[((long)(l * 512 + k)) * 512 + nn];
    } else if (n < QLD){
      v = Wg[((long)(l * 512 + k)) * 24 + (n - 1536)];
    }
    tl[ty + i * 8][tx] = v;
  }
  __syncthreads();
#pragma unroll
  for (int i = 0; i < 4; i++){
    int n = n0 + ty + i * 8, k = k0 + tx;
    if (n < QLD)
      Wb[((long)(l * QLD + n)) * 512 + k] = __float2bfloat16(tl[tx][ty + i * 8]);
  }
}

// ---------------- WO transpose (tiled): Wb[l][n][k] = Wo[l][k][n] -------------------
__global__ __launch_bounds__(256) void k_wconv2(const float* __restrict__ Wo,
                                                bf16_t* __restrict__ Wb){
  __shared__ float tl[32][33];
  int blk = blockIdx.x;              // 2 * 16 * 16
  int kt = blk & 15;
  int ntf = (blk >> 4) & 15;
  int l = blk >> 8;
  int n0 = ntf * 32, k0 = kt * 32;
  int tx = threadIdx.x & 31, ty = threadIdx.x >> 5;
#pragma unroll
  for (int i = 0; i < 4; i++)
    tl[ty + i * 8][tx] = Wo[((long)(l * 512 + k0 + ty + i * 8)) * 512 + n0 + tx];
  __syncthreads();
#pragma unroll
  for (int i = 0; i < 4; i++)
    Wb[((long)(l * 512 + n0 + ty + i * 8)) * 512 + k0 + tx] = __float2bfloat16(tl[tx][ty + i * 8]);
}

// ---------------- plain f32 -> bf16 cast ----------------
__global__ __launch_bounds__(256) void k_cast(const float* __restrict__ src,
                                              bf16_t* __restrict__ dst){
  int idx = blockIdx.x * 256 + threadIdx.x;
  dst[idx] = __float2bfloat16(src[idx]);
}

// ---------------- 16B-granular zero fill ----------------
__global__ __launch_bounds__(256) void k_zero(uintx4* __restrict__ p){
  p[blockIdx.x * 256 + threadIdx.x] = (uintx4){0u, 0u, 0u, 0u};
}

// ---------------- RMSNorm: f32 in -> bf16 out ----------------
__global__ __launch_bounds__(256) void k_rms(const float* __restrict__ X,
                                             const float* __restrict__ g,
                                             bf16_t* __restrict__ XR){
  int tok = blockIdx.x;
  int tid = threadIdx.x;
  const float* xr = X + (long)tok * DIMC;
  float v0 = xr[tid], v1 = xr[tid + 256];
  float ss = v0 * v0 + v1 * v1;
  ss = wsum(ss);
  __shared__ float red[4];
  if ((tid & 63) == 0) red[tid >> 6] = ss;
  __syncthreads();
  float tot = red[0] + red[1] + red[2] + red[3];
  float r = rsqrtf(tot * (1.0f / DIMC) + EPSF);
  XR[(long)tok * DIMC + tid]       = __float2bfloat16(v0 * r * g[tid]);
  XR[(long)tok * DIMC + tid + 256] = __float2bfloat16(v1 * r * g[tid + 256]);
}

// ---------------- LayerNorm: f32 in -> bf16 out ----------------
__global__ __launch_bounds__(256) void k_ln(const float* __restrict__ X,
                                            const float* __restrict__ g,
                                            const float* __restrict__ bb,
                                            bf16_t* __restrict__ XN){
  int tok = blockIdx.x;
  int tid = threadIdx.x;
  const float* xr = X + (long)tok * DIMC;
  float v0 = xr[tid], v1 = xr[tid + 256];
  float s = v0 + v1;
  float q = v0 * v0 + v1 * v1;
  s = wsum(s); q = wsum(q);
  __shared__ float r1[4], r2[4];
  if ((tid & 63) == 0){ r1[tid >> 6] = s; r2[tid >> 6] = q; }
  __syncthreads();
  float ts = r1[0] + r1[1] + r1[2] + r1[3];
  float tq = r2[0] + r2[1] + r2[2] + r2[3];
  float mean = ts * (1.0f / DIMC);
  float var  = tq * (1.0f / DIMC) - mean * mean;
  float rinv = rsqrtf(var + EPSF);
  XN[(long)tok * DIMC + tid]       = __float2bfloat16((v0 - mean) * rinv * g[tid]       + bb[tid]);
  XN[(long)tok * DIMC + tid + 256] = __float2bfloat16((v1 - mean) * rinv * g[tid + 256] + bb[tid + 256]);
}

// ---------------- bf16 MFMA GEMM v6: counted-vmcnt raw-barrier pipeline -------------
// (retry of R12 — no data returned; schedule re-audited: barriers block-uniform,
// vmcnt(4) counts exactly one 4-load stage, refills WAR-safe, bounds in-range.)
// R10 diagnosis: __syncthreads drains vmcnt(0), exposing the just-issued prefetch's
// full L2/HBM latency EVERY chunk (~2.5k cyc stall vs ~80 cyc MFMA). Fix (T4/AITER):
// raw s_barrier + s_waitcnt vmcnt(4) — each stage is exactly 4 gload16/thread, so
// vmcnt(4) waits the PREVIOUS stage while the newest 4 stay in flight across the
// barrier, giving the refill a full chunk (compute + 2 barriers) to land.
// Refills are issued only after the barrier ending all reads of their buffer
// (async writes post-barrier vs reads pre-barrier: WAR-safe). Tails drain vmcnt(0).
// sched_barrier(0) after each waitcnt per rule #18.
template<int OUTBF, int ACT, int BM, int TN, int BK>
__global__ __launch_bounds__(256) void k_mgemm(const bf16_t* __restrict__ A,
                                               const bf16_t* __restrict__ Bm,
                                               float* Cf,
                                               bf16_t* Cb,
                                               const float* __restrict__ bias,
                                               const float* res,
                                               int N, int K, int ldc,
                                               bf16_t* VTo){
  constexpr int MTILES = NTOK / BM;        // 98 or 49
  constexpr int MPX  = (MTILES + 7) / 8;   // m-groups per XCD (13 or 7)
  constexpr int MF   = BM / 32;            // m-frags per wave (2 or 4)
  constexpr int NF   = TN / 32;            // n-frags per wave (2 or 4)
  constexpr int KS   = BK / 32;            // k-steps per chunk (1 or 2)
  constexpr int RPB2 = 512 / BK;           // rows per 1KB wave-block
  constexpr int LPR  = BK / 8;             // lanes per row
  constexpr int ABLK = (BM * BK) / 512;    // A wave-blocks per chunk
  constexpr int BBLK = (TN * BK) / 512;    // B wave-blocks per chunk
  constexpr int TOT  = ABLK + BBLK;
  constexpr int PW   = TOT / 4;            // blocks per wave (= 4 in all configs)
  static_assert(TOT % 4 == 0, "stage blocks must split across 4 waves");
  static_assert(PW == 4, "vmcnt(4) counting assumes 4 gload16 per thread per stage");

  int id = blockIdx.x;
  int xcd = id & 7;
  int j = id >> 3;
  int nt = j / MPX;
  int mt = xcd * MPX + (j - nt * MPX);
  if (mt >= MTILES) return;
  int bm = mt * BM, bn = nt * TN;

  __shared__ bf16_t As[2][BM][BK];         // unpadded (gload_lds requires linear)
  __shared__ bf16_t Bs[2][TN][BK];
  int tid = threadIdx.x;
  int w = tid >> 6, lane = tid & 63;
  int wm = (w & 1) * (BM / 2), wn = (w >> 1) * (TN / 2);
  int quad = lane >> 4, l16 = lane & 15;

  // staging assignment: wave w owns blocks w*PW .. w*PW+PW-1 (A-blocks first)
  int lr = lane / LPR, lc = (lane % LPR) * 8;
  const bf16_t* gsrc[PW];
  bf16_t* ldst0[PW];
  bf16_t* ldst1[PW];
#pragma unroll
  for (int i = 0; i < PW; i++){
    int bi = w * PW + i;
    if (bi < ABLK){
      gsrc[i]  = A + (long)(bm + bi * RPB2 + lr) * K + lc;
      ldst0[i] = &As[0][bi * RPB2][0];
      ldst1[i] = &As[1][bi * RPB2][0];
    } else {
      int bj = bi - ABLK;
      int r = bn + bj * RPB2 + lr; if (r >= N) r = N - 1;
      gsrc[i]  = Bm + (long)r * K + lc;
      ldst0[i] = &Bs[0][bj * RPB2][0];
      ldst1[i] = &Bs[1][bj * RPB2][0];
    }
  }

  floatx4 acc[MF][NF];
#pragma unroll
  for (int i = 0; i < MF; i++)
#pragma unroll
    for (int jj = 0; jj < NF; jj++) acc[i][jj] = (floatx4)(0.0f);

#define MG_STAGE0(ko) do { _Pragma("unroll") \
    for (int i_ = 0; i_ < PW; i_++) gload16(gsrc[i_] + (ko), ldst0[i_]); } while (0)
#define MG_STAGE1(ko) do { _Pragma("unroll") \
    for (int i_ = 0; i_ < PW; i_++) gload16(gsrc[i_] + (ko), ldst1[i_]); } while (0)
#define MG_COMPUTE(BUFI) do { _Pragma("unroll") \
    for (int ks_ = 0; ks_ < KS; ks_++){ \
      bf16x8 af_[MF], bf_[NF]; \
      _Pragma("unroll") \
      for (int m_ = 0; m_ < MF; m_++) \
        af_[m_] = *(bf16x8*)&As[BUFI][wm + m_ * 16 + l16][ks_ * 32 + quad * 8]; \
      _Pragma("unroll") \
      for (int f_ = 0; f_ < NF; f_++) \
        bf_[f_] = *(bf16x8*)&Bs[BUFI][wn + f_ * 16 + l16][ks_ * 32 + quad * 8]; \
      _Pragma("unroll") \
      for (int m_ = 0; m_ < MF; m_++) \
        _Pragma("unroll") \
        for (int f_ = 0; f_ < NF; f_++) \
          acc[m_][f_] = __builtin_amdgcn_mfma_f32_16x16x32_bf16(af_[m_], bf_[f_], acc[m_][f_], 0, 0, 0); \
    } } while (0)
#define MG_WAIT4()  do { asm volatile("s_waitcnt vmcnt(4)" ::: "memory"); \
                         __builtin_amdgcn_sched_barrier(0); } while (0)
#define MG_WAIT0()  do { asm volatile("s_waitcnt vmcnt(0)" ::: "memory"); \
                         __builtin_amdgcn_sched_barrier(0); } while (0)
#define MG_BAR()    do { asm volatile("" ::: "memory"); \
                         __builtin_amdgcn_s_barrier(); \
                         asm volatile("" ::: "memory"); } while (0)

  int nch = K / BK;                        // even in all uses (16, 8, 32)
  // prologue: both buffers' loads in flight; wait only the oldest 4 (buf0)
  MG_STAGE0(0);
  MG_STAGE1(BK);
  MG_WAIT4();
  MG_BAR();
  for (int ch = 0; ch < nch; ch += 2){
    MG_COMPUTE(0);                         // chunk ch from buf0 (landed)
    MG_BAR();                              // all waves done reading buf0 (no drain!)
    if (ch + 2 < nch){
      MG_STAGE0((ch + 2) * BK);            // refill buf0: WAR-safe (post-barrier)
      MG_WAIT4();                          // buf1 (older 4) landed; refill flying
    } else {
      MG_WAIT0();                          // tail: drain buf1
    }
    MG_BAR();                              // buf1 globally ready
    MG_COMPUTE(1);                         // chunk ch+1 from buf1
    MG_BAR();                              // all waves done reading buf1
    if (ch + 3 < nch){
      MG_STAGE1((ch + 3) * BK);            // refill buf1
      MG_WAIT4();                          // buf0 refill landed
    } else if (ch + 2 < nch){
      MG_WAIT0();                          // tail: drain buf0 refill
    }
    MG_BAR();                              // buf0 (refill) globally ready
  }
#undef MG_STAGE0
#undef MG_STAGE1
#undef MG_COMPUTE
#undef MG_WAIT4
#undef MG_WAIT0
#undef MG_BAR

#pragma unroll
  for (int tm = 0; tm < MF; tm++){
#pragma unroll
    for (int tn = 0; tn < NF; tn++){
      int ncol = bn + wn + tn * 16 + l16;
      if (ncol >= N) continue;
#pragma unroll
      for (int reg = 0; reg < 4; reg++){
        long mrow = bm + wm + tm * 16 + quad * 4 + reg;
        float v = acc[tm][tn][reg];
        if (bias) v += bias[ncol];
        if (ACT == 1) v = geluf(v);
        long off = mrow * (long)ldc + ncol;
        if (res) v += res[off];
        if (OUTBF){
          Cb[off] = __float2bfloat16(v);
          if (VTo && ncol >= 1024 && ncol < 1536){
            int bb2 = (int)(mrow / SEQ_);
            int tok = (int)(mrow - (long)bb2 * SEQ_);
            VTo[((long)(bb2 * 512 + (ncol - 1024))) * 800 + tok] = __float2bfloat16(v);
          }
        }
        else       Cf[off] = v;
      }
    }
  }
}

// ---------------- compressed-block mean pooling v2: 8-way channel split -------------
__global__ __launch_bounds__(256) void k_cpool(const bf16_t* __restrict__ qkvg,
                                               float* __restrict__ ck,
                                               float* __restrict__ cv){
  int blk = blockIdx.x;          // B_*NC_*8
  int cs = blk & 7;
  int bj = blk >> 3;
  int j = bj % NC_;
  int b = bj / NC_;
  int tid = threadIdx.x;
  int seg = tid & 15;            // 16 lanes x 8 ch = 128 channels
  int rg  = tid >> 4;            // 16 row-groups
  __shared__ float part[16][128];
  const bf16_t* base = qkvg + ((long)b * SEQ_ + (long)j * CST_) * QLD + 512 + cs * 128;
  float acc[8] = {0.f,0.f,0.f,0.f,0.f,0.f,0.f,0.f};
  for (int r = rg; r < CBS_; r += 16){
    uintx4 v = *(const uintx4*)(base + (long)r * QLD + seg * 8);
    bf16_t tmp[8]; *(uintx4*)tmp = v;
#pragma unroll
    for (int q = 0; q < 8; q++) acc[q] += __bfloat162float(tmp[q]);
  }
#pragma unroll
  for (int q = 0; q < 8; q++) part[rg][seg * 8 + q] = acc[q];
  __syncthreads();
  if (tid < 128){
    float s = 0.f;
#pragma unroll
    for (int g = 0; g < 16; g++) s += part[g][tid];
    s *= (1.0f / CBS_);
    int gch = cs * 128 + tid;
    if (gch < 512) ck[bj * DIMC + gch] = s;
    else           cv[bj * DIMC + (gch - 512)] = s;
  }
}

// ---------------- fused NSA attention v11 (frozen; 57.9 us) -------------------------
__global__ __launch_bounds__(256) void k_attn(const bf16_t* __restrict__ qkvg,
                                              const float* __restrict__ ck,
                                              const float* __restrict__ cv,
                                              const bf16_t* __restrict__ vtg,
                                              bf16_t* __restrict__ oattn){
  int tid = threadIdx.x;
  int w = tid >> 6, lane = tid & 63;
  int quad = lane >> 4, l16 = lane & 15;
  int id = blockIdx.x;
  int xcd = id & 7;
  int j = id >> 3;               // 0..223
  int bh = xcd * 8 + (j / 28);   // all 28 tiles of a bh on one XCD
  int i0 = (j % 28) * TQ_;
  int h = bh & 7, b = bh >> 3;
  const float scale = 0.125f;

  __shared__ bf16_t Qs[32][72];          // rows 28-31 zero
  __shared__ bf16_t Ks[2][64][72];       // K dbuf
  __shared__ bf16_t Wcw[2][32][72];      // win-masked W dbuf (rows 28-31 zero)
  __shared__ bf16_t Wcs[2][32][72];      // sel-masked W dbuf (rows 28-31 zero)
  __shared__ float outc_s[28][64];
  __shared__ int   sel_s[28];
  __shared__ float cw_s[28], cs_s[28], g1_s[28], g2_s[28];
  __shared__ float red_s[4][4][16];

  const long rowBase = (long)b * SEQ_ * QLD + h * 64;     // + token*QLD + {0,512,1024}

  // ---- Phase A: stage Q tile (28 rows) + zero rows 28-31; zero Wc rows 28-31 ----
  if (tid < 224){
    int q = tid >> 3, seg = tid & 7;
    uintx4 qv = *(const uintx4*)(qkvg + rowBase + (long)(i0 + q) * QLD + seg * 8);
    *(uintx4*)&Qs[q][seg * 8] = qv;
  } else {
    int u = tid - 224;
    int r = 28 + (u >> 3), seg = u & 7;
    *(uintx4*)&Qs[r][seg * 8] = (uintx4){0u, 0u, 0u, 0u};
  }
  for (int t = tid; t < 2 * 4 * 72; t += 256){
    int bufi = t / (4 * 72);
    int r = 28 + (t / 72) % 4;
    int c = t % 72;
    Wcw[bufi][r][c] = __float2bfloat16(0.0f);
    Wcs[bufi][r][c] = __float2bfloat16(0.0f);
  }
  __syncthreads();

  // ---- prefetch K chunk 0 (latency hidden under Phase B) ----
  int r0i = tid >> 3, s0i = tid & 7;
  int r1i = 32 + r0i;
  uintx4 kreg0 = *(const uintx4*)(qkvg + rowBase + (long)r0i * QLD + 512 + s0i * 8);
  uintx4 kreg1 = *(const uintx4*)(qkvg + rowBase + (long)r1i * QLD + 512 + s0i * 8);

  // ---- Phase B: compressed branch + gates + top-1 selection ----
  {
    const float* CKp = ck + (long)b * NC_ * DIMC + h * 64 + lane;
    const float* CVp = cv + (long)b * NC_ * DIMC + h * 64 + lane;
    float k0 = CKp[0], k1 = CKp[512], k2 = CKp[1024];
    float v0 = CVp[0], v1 = CVp[512], v2 = CVp[1024];
#pragma unroll
    for (int qp = 0; qp < 7; qp++){
      int qg = w * 7 + qp;
      float qd = __bfloat162float(Qs[qg][lane]);
      float s0 = wsum(qd * k0) * scale;
      float s1 = wsum(qd * k1) * scale;
      float s2 = wsum(qd * k2) * scale;
      float m3 = fmaxf(s0, fmaxf(s1, s2));
      float e0 = __expf(s0 - m3), e1 = __expf(s1 - m3), e2 = __expf(s2 - m3);
      float inv = 1.0f / (e0 + e1 + e2);
      const bf16_t* grow = qkvg + (long)(b * SEQ_ + i0 + qg) * QLD + 1536 + h * 3;
      float g0 = sigmoidf_(__bfloat162float(grow[0]));
      float g1v = sigmoidf_(__bfloat162float(grow[1]));
      float g2v = sigmoidf_(__bfloat162float(grow[2]));
      outc_s[qg][lane] = g0 * (e0 * v0 + e1 * v1 + e2 * v2) * inv;
      int selv = (s2 > s0) ? 1 : 0;   // imp1>imp0 <=> p2>p0 <=> s2>s0
      if (lane == 0){ sel_s[qg] = selv; g1_s[qg] = g1v; g2_s[qg] = g2v; }
    }
  }

  // hoist Q B-fragments (chunk-invariant)
  bf16x8 a00 = *(bf16x8*)&Qs[l16][quad * 8];
  bf16x8 a01 = *(bf16x8*)&Qs[l16][32 + quad * 8];
  bf16x8 a10 = *(bf16x8*)&Qs[16 + l16][quad * 8];
  bf16x8 a11 = *(bf16x8*)&Qs[16 + l16][32 + quad * 8];

  __syncthreads();   // sel_s/g1_s/g2_s visible; Wc zero rows done

  // ---- selection-half usage flags (block-uniform) ----
  int nsel1 = 0;
#pragma unroll
  for (int q = 0; q < 28; q++) nsel1 += sel_s[q];
  const bool any0 = (nsel1 < 28), any1 = (nsel1 > 0);

  // ---- main loop: 13 chunks of 64 keys, fused QK^T + masked-W + PV ----------------
  int sel0i = sel_s[l16];
  int sel1i = (l16 < 12) ? sel_s[16 + l16] : 0;
  bool sv0 = (sel0i != 0), sv1 = (sel1i != 0);
  int iq0 = i0 + l16, iq1 = i0 + 16 + l16;
  float sw0 = 0.f, ss0 = 0.f, sw1 = 0.f, ss1 = 0.f;

  const bf16_t* vbase = vtg + ((long)(b * 512 + h * 64 + w * 16 + l16)) * 800;
  floatx4 ow0 = (floatx4)(0.0f), ow1 = (floatx4)(0.0f);
  floatx4 os0 = (floatx4)(0.0f), os1 = (floatx4)(0.0f);

  for (int ch = 0; ch < 13; ch++){
    int buf = ch & 1;
    int K0 = ch * 64;
    // block-uniform activity flags for this chunk
    bool wact = (K0 + 63 >= i0 - 195) && (K0 <= i0 + 222);
    bool sact = ((K0 <= 391) && any0) || ((K0 + 63 >= 392) && any1);
    bool pact = wact || sact;
    // stage K chunk
    *(uintx4*)&Ks[buf][r0i][s0i * 8] = kreg0;
    *(uintx4*)&Ks[buf][r1i][s0i * 8] = kreg1;
    __syncthreads();                               // barrier A
    // prefetch next K chunk
    if (ch + 1 < 13){
      int c0n = (ch + 1) * 64;
      int t0 = c0n + r0i; if (t0 > 783) t0 = 783;
      int t1 = c0n + r1i; if (t1 > 783) t1 = 783;
      kreg0 = *(const uintx4*)(qkvg + rowBase + (long)t0 * QLD + 512 + s0i * 8);
      kreg1 = *(const uintx4*)(qkvg + rowBase + (long)t1 * QLD + 512 + s0i * 8);
    }
    // V^T fragments for this chunk (latency hides under QK^T+exp)
    int tv0 = K0 + quad * 8;      if (tv0 > 792) tv0 = 792;
    int tv1 = K0 + 32 + quad * 8; if (tv1 > 792) tv1 = 792;
    bf16x8 bv0 = *(const bf16x8*)(vbase + tv0);
    bf16x8 bv1 = *(const bf16x8*)(vbase + tv1);
    if (pact){
      // QK^T (S^T layout: lane holds q=l16 / 16+l16, keys K0+w*16+quad*4+{0..3})
      bf16x8 k0 = *(bf16x8*)&Ks[buf][w * 16 + l16][quad * 8];
      bf16x8 k1 = *(bf16x8*)&Ks[buf][w * 16 + l16][32 + quad * 8];
      floatx4 d0 = (floatx4)(0.0f), d1 = (floatx4)(0.0f);
      d0 = __builtin_amdgcn_mfma_f32_16x16x32_bf16(k0, a00, d0, 0, 0, 0);
      d0 = __builtin_amdgcn_mfma_f32_16x16x32_bf16(k1, a01, d0, 0, 0, 0);
      d1 = __builtin_amdgcn_mfma_f32_16x16x32_bf16(k0, a10, d1, 0, 0, 0);
      d1 = __builtin_amdgcn_mfma_f32_16x16x32_bf16(k1, a11, d1, 0, 0, 0);
      int kb = K0 + w * 16 + quad * 4;
      float ex0[4], ex1[4];
#pragma unroll
      for (int r = 0; r < 4; r++){
        ex0[r] = __expf(d0[r] * scale);
        ex1[r] = __expf(d1[r] * scale);
      }
      int kloc = w * 16 + quad * 4;
      if (wact){
        union { bf16_t hh[4]; uintx2 v; } pw0, pw1;
#pragma unroll
        for (int r = 0; r < 4; r++){
          int key = kb + r;
          bool valid = key < 784;
          float vw0 = (valid && key >= iq0 - 195 && key <= iq0 + 195) ? ex0[r] : 0.0f;
          float vw1 = (valid && key >= iq1 - 195 && key <= iq1 + 195) ? ex1[r] : 0.0f;
          sw0 += vw0; sw1 += vw1;
          pw0.hh[r] = __float2bfloat16(vw0);
          pw1.hh[r] = __float2bfloat16(vw1);
        }
        if (kb < 784){
          *(uintx2*)&Wcw[buf][l16][kloc] = pw0.v;
          if (l16 < 12) *(uintx2*)&Wcw[buf][16 + l16][kloc] = pw1.v;
        }
      }
      if (sact){
        union { bf16_t hh[4]; uintx2 v; } ps0, ps1;
#pragma unroll
        for (int r = 0; r < 4; r++){
          int key = kb + r;
          bool valid = key < 784;
          float vs0 = (valid && ((key >= 392) == sv0)) ? ex0[r] : 0.0f;
          float vs1 = (valid && ((key >= 392) == sv1)) ? ex1[r] : 0.0f;
          ss0 += vs0; ss1 += vs1;
          ps0.hh[r] = __float2bfloat16(vs0);
          ps1.hh[r] = __float2bfloat16(vs1);
        }
        if (kb < 784){
          *(uintx2*)&Wcs[buf][l16][kloc] = ps0.v;
          if (l16 < 12) *(uintx2*)&Wcs[buf][16 + l16][kloc] = ps1.v;
        }
      }
    }
    __syncthreads();                               // barrier B
    // PV: wave w owns d = w*16+l16; A = Wc rows (q), B = V^T
    if (wact){
#pragma unroll
      for (int ks = 0; ks < 2; ks++){
        bf16x8 bv = ks ? bv1 : bv0;
        bf16x8 aw0 = *(bf16x8*)&Wcw[buf][l16][ks * 32 + quad * 8];
        bf16x8 aw1 = *(bf16x8*)&Wcw[buf][16 + l16][ks * 32 + quad * 8];
        ow0 = __builtin_amdgcn_mfma_f32_16x16x32_bf16(aw0, bv, ow0, 0, 0, 0);
        ow1 = __builtin_amdgcn_mfma_f32_16x16x32_bf16(aw1, bv, ow1, 0, 0, 0);
      }
    }
    if (sact){
#pragma unroll
      for (int ks = 0; ks < 2; ks++){
        bf16x8 bv = ks ? bv1 : bv0;
        bf16x8 as0 = *(bf16x8*)&Wcs[buf][l16][ks * 32 + quad * 8];
        bf16x8 as1 = *(bf16x8*)&Wcs[buf][16 + l16][ks * 32 + quad * 8];
        os0 = __builtin_amdgcn_mfma_f32_16x16x32_bf16(as0, bv, os0, 0, 0, 0);
        os1 = __builtin_amdgcn_mfma_f32_16x16x32_bf16(as1, bv, os1, 0, 0, 0);
      }
    }
  }

  // ---- combine row sums: quads via shfl, waves via 1KB LDS ----
  sw0 += __shfl_xor(sw0, 16, 64); sw0 += __shfl_xor(sw0, 32, 64);
  ss0 += __shfl_xor(ss0, 16, 64); ss0 += __shfl_xor(ss0, 32, 64);
  sw1 += __shfl_xor(sw1, 16, 64); sw1 += __shfl_xor(sw1, 32, 64);
  ss1 += __shfl_xor(ss1, 16, 64); ss1 += __shfl_xor(ss1, 32, 64);
  if (quad == 0){
    red_s[w][0][l16] = sw0; red_s[w][1][l16] = ss0;
    red_s[w][2][l16] = sw1; red_s[w][3][l16] = ss1;
  }
  __syncthreads();
  if (tid < 28){
    int q = tid, t = q >> 4, l = q & 15;
    float sw = 0.f, ss = 0.f;
#pragma unroll
    for (int wv = 0; wv < 4; wv++){ sw += red_s[wv][2 * t][l]; ss += red_s[wv][2 * t + 1][l]; }
    cw_s[q] = g2_s[q] / sw;
    cs_s[q] = g1_s[q] / ss;
  }
  __syncthreads();

  // ---- epilogue: scale branches, add compressed branch, write bf16 ----
  int d = w * 16 + l16;
#pragma unroll
  for (int reg = 0; reg < 4; reg++){
    int q = quad * 4 + reg;
    float o = cw_s[q] * ow0[reg] + cs_s[q] * os0[reg] + outc_s[q][d];
    oattn[((long)(b * SEQ_ + i0 + q)) * DIMC + h * 64 + d] = __float2bfloat16(o);
    int q2 = q + 16;
    if (q2 < 28){
      float o2 = cw_s[q2] * ow1[reg] + cs_s[q2] * os1[reg] + outc_s[q2][d];
      oattn[((long)(b * SEQ_ + i0 + q2)) * DIMC + h * 64 + d] = __float2bfloat16(o2);
    }
  }
}

// ---------------- host launcher ----------------
extern "C" void kernel_launch(void* const* d_in, const int* in_sizes, int n_in,
                              void* d_out, int out_size, void* d_ws, size_t ws_size,
                              hipStream_t stream){
  const float* xin  = (const float*)d_in[0];
  const float* pos  = (const float*)d_in[1];
  const float* angm = (const float*)d_in[2];
  const float* Wq   = (const float*)d_in[3];
  const float* Wk   = (const float*)d_in[4];
  const float* Wv   = (const float*)d_in[5];
  const float* Wo   = (const float*)d_in[6];
  const float* Wg   = (const float*)d_in[7];
  const float* fng  = (const float*)d_in[8];
  const float* fnb  = (const float*)d_in[9];
  const float* fw1  = (const float*)d_in[10];
  const float* fb1  = (const float*)d_in[11];
  const float* fw2  = (const float*)d_in[12];
  const float* fb2  = (const float*)d_in[13];

  // workspace layout: ~70.7 MB total (BUFb/H1b share one region — disjoint live ranges)
  char* cw = (char*)d_ws;
  float* X = (float*)cw;             cw += (long)NTOK * 512 * 4;     // 12.85 MB
  bf16_t* XRb = (bf16_t*)cw;         cw += (long)NTOK * 512 * 2;     //  6.42 MB
  bf16_t* OAb = (bf16_t*)cw;         cw += (long)NTOK * 512 * 2;     //  6.42 MB
  bf16_t* SH  = (bf16_t*)cw;         cw += (long)NTOK * FF_ * 2;     // 25.69 MB (BUFb/H1b)
  float* CK = (float*)cw;            cw += (long)B_ * NC_ * DIMC * 4;
  float* CV = (float*)cw;            cw += (long)B_ * NC_ * DIMC * 4;
  bf16_t* Wqkvgb = (bf16_t*)cw;      cw += (long)2 * QLD * 512 * 2;  //  3.19 MB
  bf16_t* WOb    = (bf16_t*)cw;      cw += (long)2 * 512 * 512 * 2;  //  1.05 MB
  bf16_t* FW1b   = (bf16_t*)cw;      cw += (long)2 * FF_ * 512 * 2;  //  4.19 MB
  bf16_t* FW2b   = (bf16_t*)cw;      cw += (long)2 * 512 * FF_ * 2;  //  4.19 MB
  bf16_t* VTb    = (bf16_t*)cw;      cw += (long)B_ * 512 * 800 * 2; //  6.55 MB
  bf16_t* BUFb = SH;   // [NTOK, QLD]  (QKVG output; dies after k_attn)
  bf16_t* H1b  = SH;   // [NTOK, FF_]  (FF1 output; born after k_ln)

  // per-call weight conversion (deterministic, same work every call)
  k_wconv1<<<2 * 49 * 16, 256, 0, stream>>>(Wq, Wk, Wv, Wg, Wqkvgb);
  k_wconv2<<<2 * 16 * 16, 256, 0, stream>>>(Wo, WOb);
  k_cast<<<(2 * FF_ * 512) / 256, 256, 0, stream>>>(fw1, FW1b);
  k_cast<<<(2 * 512 * FF_) / 256, 256, 0, stream>>>(fw2, FW2b);

  // zero VT once: tokens 784..799 stay zero; cols 0..783 rewritten each layer
  k_zero<<<1600, 256, 0, stream>>>((uintx4*)VTb);   // 6,553,600 B

  k_init<<<8 * 25 * 16, 256, 0, stream>>>(xin, pos, X);

  for (int l = 0; l < 2; l++){
    k_rms<<<NTOK, 256, 0, stream>>>(X, angm + (long)l * DIMC, XRb);

    // fused QKV+G GEMM: [6272,512] x [1560,512]^T -> BUFb [6272,1560] bf16 (+ VT)
    k_mgemm<1, 0, 128, 128, 32><<<13 * 56, 256, 0, stream>>>(
        XRb, Wqkvgb + (long)l * QLD * 512, nullptr, BUFb, nullptr, nullptr,
        QLD, 512, QLD, VTb);

    k_cpool<<<B_ * NC_ * 8, 256, 0, stream>>>(BUFb, CK, CV);

    k_attn<<<8 * 8 * 28, 256, 0, stream>>>(BUFb, CK, CV, VTb, OAb);

    // Wo GEMM: f32 out + residual into X (64x64x64, grid 832)
    k_mgemm<0, 0, 64, 64, 64><<<8 * 104, 256, 0, stream>>>(
        OAb, WOb + (long)l * 512 * 512, X, nullptr, nullptr, X,
        512, 512, 512, nullptr);

    k_ln<<<NTOK, 256, 0, stream>>>(X, fng + (long)l * DIMC, fnb + (long)l * DIMC, XRb);

    // FF1 + GELU, bf16 out into H1b (BM=128, grid 16 nt x 56)
    k_mgemm<1, 1, 128, 128, 32><<<16 * 56, 256, 0, stream>>>(
        XRb, FW1b + (long)l * FF_ * 512, nullptr, H1b, fb1 + (long)l * FF_, nullptr,
        FF_, 512, FF_, nullptr);
    // FF2, f32 out + residual into X (64x64x64, grid 832)
    k_mgemm<0, 0, 64, 64, 64><<<8 * 104, 256, 0, stream>>>(
        H1b, FW2b + (long)l * 512 * FF_, X, nullptr, fb2 + (long)l * DIMC, X,
        512, FF_, 512, nullptr);
  }

  k_final<<<8 * 25 * 16, 256, 0, stream>>>(X, (float*)d_out);
}